// Round 3
// baseline (8806.715 us; speedup 1.0000x reference)
//
#include <hip/hip_runtime.h>
#include <stdint.h>

// ---------------------------------------------------------------------------
// LSTM-VAE persistent kernel, MI355X (gfx950).  B=128, T=512, I=L=64, H=512,
// 100 decoder steps.  fp32 in/out (per reference dtypes); bf16 MFMA internal.
//
// Grid: 128 WGs = 8 batch-groups(g) x 16 hidden-slices(s), block=512 (8 waves).
// Each slice owns 32 hidden dims = 128 gate rows. Gate rows interleaved
// [i0,f0,g0,o0, i1,...] so one 16x16 MFMA C-tile holds all 4 gates of 4 dims
// -> cell update needs only 3 quad shuffles.  W_hh slice (128x512) lives in
// 64 VGPRs/lane as loop-invariant MFMA B-fragments (no big LDS).
// Decoder folds x_hat via W_comb = W_hh_dec + W_ih_dec@W_out (h-only
// recurrence, one barrier/step); x_hat emitted inline by slice 0.
// Inter-WG sync per group: release fence+add, relaxed spin, acquire fence.
// h exchanged through ws as bf16 via plain uint4 ops (fences do L2 wb/inv).
// ---------------------------------------------------------------------------

typedef short short8 __attribute__((ext_vector_type(8)));
typedef float f32x4 __attribute__((ext_vector_type(4)));

#define WS_CNT    0
#define WS_HBUF0  4096
#define WS_HBUF1  135168
#define WS_Z      266240
#define WS_BCOMB  299008
#define WS_WCOMB  307200
// ws bytes used: 307200 + 2*1024*1024 = 2404352 (~2.3 MB)

static __device__ __forceinline__ float b2f(unsigned short u) {
    return __builtin_bit_cast(float, (unsigned int)u << 16);
}
static __device__ __forceinline__ unsigned short f2b(float f) {
    unsigned int u = __builtin_bit_cast(unsigned int, f);
    unsigned int r = u + 0x7FFFu + ((u >> 16) & 1u);  // RNE
    return (unsigned short)(r >> 16);
}
static __device__ __forceinline__ float sigm(float x)  { return 1.0f / (1.0f + __expf(-x)); }
static __device__ __forceinline__ float tanhx(float x) { return 1.0f - 2.0f / (__expf(2.0f * x) + 1.0f); }

// convert 8 consecutive fp32 (32B-aligned) to a bf16 short8 fragment
static __device__ __forceinline__ short8 cvt8(const float* p) {
    const float4 a = ((const float4*)p)[0];
    const float4 b = ((const float4*)p)[1];
    short8 r;
    r[0] = (short)f2b(a.x); r[1] = (short)f2b(a.y);
    r[2] = (short)f2b(a.z); r[3] = (short)f2b(a.w);
    r[4] = (short)f2b(b.x); r[5] = (short)f2b(b.y);
    r[6] = (short)f2b(b.z); r[7] = (short)f2b(b.w);
    return r;
}

// ---------------------------------------------------------------------------
// Kernel 1: W_comb = W_hh_dec + W_ih_dec @ W_out (bf16 out), b_comb (fp32)
// ---------------------------------------------------------------------------
__global__ void __launch_bounds__(256)
wcomb_kernel(const float* __restrict__ Wih_d,
             const float* __restrict__ Whh_d,
             const float* __restrict__ Wout,
             const float* __restrict__ bih_d,
             const float* __restrict__ bhh_d,
             const float* __restrict__ bout,
             unsigned char* __restrict__ ws)
{
    __shared__ float Ash[64][64];   // W_ih_dec tile [g][i]
    __shared__ float Bsh[64][65];   // W_out tile [i][h]
    const int bid = blockIdx.x, t = threadIdx.x;
    const int gt0 = (bid >> 3) * 64, ht0 = (bid & 7) * 64;
    for (int j = 0; j < 16; ++j) {
        int idx = t + j * 256;          // 0..4095
        int r = idx >> 6, c = idx & 63;
        Ash[r][c] = Wih_d[(size_t)(gt0 + r) * 64 + c];
        Bsh[r][c] = Wout[(size_t)r * 512 + ht0 + c];
    }
    __syncthreads();
    const int gl = t >> 2, hl0 = (t & 3) * 16;
    for (int hh = 0; hh < 16; ++hh) {
        float acc = 0.f;
        #pragma unroll
        for (int i = 0; i < 64; ++i) acc += Ash[gl][i] * Bsh[i][hl0 + hh];
        int g = gt0 + gl, h = ht0 + hl0 + hh;
        float v = Whh_d[(size_t)g * 512 + h] + acc;
        ((unsigned short*)(ws + WS_WCOMB))[(size_t)g * 512 + h] = f2b(v);
    }
    if ((bid & 7) == 0 && t < 64) {
        int g = gt0 + t;
        float acc = bih_d[g] + bhh_d[g];
        #pragma unroll
        for (int i = 0; i < 64; ++i) acc += bout[i] * Ash[t][i];
        ((float*)(ws + WS_BCOMB))[g] = acc;
    }
}

// ---------------------------------------------------------------------------
// Kernel 2: persistent encoder + VAE + decoder (emits x_hat inline)
// ---------------------------------------------------------------------------
__global__ void __launch_bounds__(512, 2)
vae_persistent(const float* __restrict__ seq,
               const float* __restrict__ eps,
               const float* __restrict__ Wih_e,
               const float* __restrict__ Whh_e,
               const float* __restrict__ bih_e,
               const float* __restrict__ bhh_e,
               const float* __restrict__ Wmean,
               const float* __restrict__ bmean,
               const float* __restrict__ Wlv,
               const float* __restrict__ blv,
               const float* __restrict__ Winit,
               const float* __restrict__ binit,
               const float* __restrict__ Whh_d,
               const float* __restrict__ bih_d,
               const float* __restrict__ bhh_d,
               const float* __restrict__ Wout,
               const float* __restrict__ bout,
               unsigned char* __restrict__ ws,
               float* __restrict__ out)
{
    __shared__ __align__(16) short Al[16 * 520];  // staged h tile (bf16), stride 520
    __shared__ __align__(16) short Ho[512];       // h write-back staging [16][32]
    __shared__ float fbuf[128];                   // mean/logvar scratch
    __shared__ float zl[16 * 64];                 // z tile (fp32)

    const int tid  = threadIdx.x;
    const int g    = blockIdx.x & 7;        // batch group
    const int s    = blockIdx.x >> 3;       // hidden slice
    const int b0   = g * 16;
    const int lane = tid & 63;
    const int wv   = tid >> 6;              // wave 0..7
    const int col  = lane & 15;
    const int q    = lane >> 4;
    const int nloc = wv * 16 + col;         // interleaved gate column 0..127
    const int gt   = nloc & 3;              // 0=i,1=f,2=g,3=o
    const int hds  = nloc >> 2;             // hidden dim within slice
    const int grow = gt * 512 + s * 32 + hds;   // global gate row in [0,2048)

    uint32_t* cnt = (uint32_t*)(ws + WS_CNT) + g * 32;
    uint4* hbuf0 = (uint4*)(ws + WS_HBUF0);
    uint4* hbuf1 = (uint4*)(ws + WS_HBUF1);

    int epoch = 0;
    float cst[4] = {0.f, 0.f, 0.f, 0.f};    // fp32 cell state (4 batch rows)

    auto barrier = [&]() {
        ++epoch;
        __syncthreads();                     // drains this WG's vmem
        if (tid == 0) {
            __builtin_amdgcn_fence(__ATOMIC_RELEASE, "agent");
            __hip_atomic_fetch_add(cnt, 1u, __ATOMIC_RELEASE, __HIP_MEMORY_SCOPE_AGENT);
            while (__hip_atomic_load(cnt, __ATOMIC_ACQUIRE, __HIP_MEMORY_SCOPE_AGENT)
                   < (uint32_t)(16 * epoch))
                __builtin_amdgcn_s_sleep(2);
        }
        __syncthreads();
        __builtin_amdgcn_fence(__ATOMIC_ACQUIRE, "agent");
    };

    // stage h[b0..b0+16][0:512] (bf16) from hbuf[p] into Al
    auto stage_h = [&](int p) {
        const uint4* src = p ? hbuf1 : hbuf0;
        #pragma unroll
        for (int j = 0; j < 2; ++j) {
            int idx = tid + j * 512;             // 0..1023
            int b = idx >> 6, c4 = idx & 63;
            ((uint4*)Al)[b * 65 + c4] = src[(size_t)(b0 + b) * 64 + c4];
        }
        __syncthreads();
    };

    // loop-invariant B-fragments of the 128x512 weight slice (64 VGPRs)
    short8 wfrag[16];
    auto load_wfrag_f32 = [&](const float* Wsrc) {
        #pragma unroll
        for (int kt = 0; kt < 16; ++kt)
            wfrag[kt] = cvt8(Wsrc + (size_t)grow * 512 + kt * 32 + q * 8);
    };
    auto load_wfrag_bf16 = [&](const unsigned short* Wsrc) {
        #pragma unroll
        for (int kt = 0; kt < 16; ++kt)
            wfrag[kt] = *(const short8*)((const short*)Wsrc +
                         (size_t)grow * 512 + kt * 32 + q * 8);
    };

    // activations + cell update + bf16 h write-back to hbuf[p_write]
    auto cell_update = [&](f32x4 acc, int p_write) {
        float act[4];
        #pragma unroll
        for (int r = 0; r < 4; ++r)
            act[r] = (gt == 2) ? tanhx(acc[r]) : sigm(acc[r]);
        int base = lane & ~3;
        #pragma unroll
        for (int r = 0; r < 4; ++r) {
            float vi = __shfl(act[r], base + 0);
            float vf = __shfl(act[r], base + 1);
            float vg = __shfl(act[r], base + 2);
            float vo = __shfl(act[r], base + 3);
            cst[r] = vf * cst[r] + vi * vg;
            act[r] = vo * tanhx(cst[r]);         // now h
        }
        if (gt == 0) {
            int hd4 = wv * 4 + (col >> 2);       // == hds, 0..31
            #pragma unroll
            for (int r = 0; r < 4; ++r)
                Ho[(q * 4 + r) * 32 + hd4] = (short)f2b(act[r]);
        }
        __syncthreads();
        if (tid < 64) {                          // 16 b x 4 uint4 = 32 dims
            int b = tid >> 2, q4 = tid & 3;
            uint4* dst = p_write ? hbuf1 : hbuf0;
            dst[(size_t)(b0 + b) * 64 + s * 4 + q4] = ((const uint4*)Ho)[b * 4 + q4];
        }
    };

    // ---------------- encoder: 512 steps ----------------
    load_wfrag_f32(Whh_e);
    short8 xwf[2];
    #pragma unroll
    for (int kt = 0; kt < 2; ++kt)
        xwf[kt] = cvt8(Wih_e + (size_t)grow * 64 + kt * 32 + q * 8);
    const float bias_e = bih_e[grow] + bhh_e[grow];

    short8 xf[2];
    {   // prefetch x for t=0
        const float* xs = seq + ((size_t)(b0 + col) * 512 + 0) * 64 + q * 8;
        xf[0] = cvt8(xs);
        xf[1] = cvt8(xs + 32);
    }
    for (int t = 0; t < 512; ++t) {
        stage_h(t & 1);
        f32x4 acc = {bias_e, bias_e, bias_e, bias_e};
        acc = __builtin_amdgcn_mfma_f32_16x16x32_bf16(xf[0], xwf[0], acc, 0, 0, 0);
        acc = __builtin_amdgcn_mfma_f32_16x16x32_bf16(xf[1], xwf[1], acc, 0, 0, 0);
        if (t < 511) {                           // prefetch x for t+1
            const float* xs = seq + ((size_t)(b0 + col) * 512 + t + 1) * 64 + q * 8;
            xf[0] = cvt8(xs);
            xf[1] = cvt8(xs + 32);
        }
        #pragma unroll
        for (int kt = 0; kt < 16; ++kt) {
            short8 a = *(const short8*)(Al + col * 520 + kt * 32 + q * 8);
            acc = __builtin_amdgcn_mfma_f32_16x16x32_bf16(a, wfrag[kt], acc, 0, 0, 0);
        }
        cell_update(acc, (t + 1) & 1);
        barrier();
    }
    // h_n now in hbuf0

    // ---------------- VAE reparameterization ----------------
    stage_h(0);
    if (tid < 128) {
        int which = tid >> 6, idx = tid & 63;
        int b = idx >> 2, ldl = idx & 3;
        int ld = s * 4 + ldl;
        const float* wrow = (which ? Wlv : Wmean) + (size_t)ld * 512;
        float a = (which ? blv[ld] : bmean[ld]);
        for (int k = 0; k < 512; ++k)
            a += b2f((unsigned short)Al[b * 520 + k]) * wrow[k];
        out[819200 + which * 8192 + (size_t)(b0 + b) * 64 + ld] = a;
        fbuf[which * 64 + idx] = a;
    }
    __syncthreads();
    if (tid < 64) {
        int b = tid >> 2, ldl = tid & 3;
        int ld = s * 4 + ldl;
        float m = fbuf[tid], lv = fbuf[64 + tid];
        float e = eps[(size_t)(b0 + b) * 64 + ld];
        ((float*)(ws + WS_Z))[(size_t)(b0 + b) * 64 + ld] = m + e * __expf(0.5f * lv);
    }
    barrier();                                   // z visible group-wide

    // h_dec0 = z @ W_init^T + b_init
    #pragma unroll
    for (int j = 0; j < 2; ++j) {
        int idx = tid + j * 512;
        int b = idx >> 6, l = idx & 63;
        zl[b * 64 + l] = ((const float*)(ws + WS_Z))[(size_t)(b0 + b) * 64 + l];
    }
    __syncthreads();
    {
        int b = tid >> 5, hdl = tid & 31;
        int hd = s * 32 + hdl;
        float a = binit[hd];
        const float* wr = Winit + (size_t)hd * 64;
        #pragma unroll
        for (int l = 0; l < 64; ++l) a += zl[b * 64 + l] * wr[l];
        Ho[b * 32 + hdl] = (short)f2b(a);
    }
    __syncthreads();
    if (tid < 64) {
        int b = tid >> 2, q4 = tid & 3;
        hbuf1[(size_t)(b0 + b) * 64 + s * 4 + q4] = ((const uint4*)Ho)[b * 4 + q4];
    }
    #pragma unroll
    for (int r = 0; r < 4; ++r) cst[r] = 0.f;
    barrier();                                   // h_dec0 visible (in hbuf1)

    // ---------------- decoder: 100 steps + inline x_hat ----------------
    short8 wof[16];
    float xbias = 0.f;
    if (wv < 4) {                                // x_hat fragments (waves 0-3)
        xbias = bout[wv * 16 + col];
        #pragma unroll
        for (int kt = 0; kt < 16; ++kt)
            wof[kt] = cvt8(Wout + (size_t)(wv * 16 + col) * 512 + kt * 32 + q * 8);
    }
    auto xhat_emit = [&](int d) {                // x_hat_d from Al (s==0, wv<4)
        f32x4 a2 = {xbias, xbias, xbias, xbias};
        #pragma unroll
        for (int kt = 0; kt < 16; ++kt) {
            short8 a = *(const short8*)(Al + col * 520 + kt * 32 + q * 8);
            a2 = __builtin_amdgcn_mfma_f32_16x16x32_bf16(a, wof[kt], a2, 0, 0, 0);
        }
        #pragma unroll
        for (int r = 0; r < 4; ++r) {
            int b = q * 4 + r;
            out[((size_t)(b0 + b) * 100 + d) * 64 + wv * 16 + col] = a2[r];
        }
    };

    load_wfrag_f32(Whh_d);                       // step 0: x0 == 0
    float bias = bih_d[grow] + bhh_d[grow];
    for (int d = 0; d < 100; ++d) {
        stage_h((d + 1) & 1);                    // Al = h_{d-1} (or h_dec0)
        if (d >= 1 && s == 0 && wv < 4) xhat_emit(d - 1);
        f32x4 acc = {bias, bias, bias, bias};
        #pragma unroll
        for (int kt = 0; kt < 16; ++kt) {
            short8 a = *(const short8*)(Al + col * 520 + kt * 32 + q * 8);
            acc = __builtin_amdgcn_mfma_f32_16x16x32_bf16(a, wfrag[kt], acc, 0, 0, 0);
        }
        cell_update(acc, d & 1);
        barrier();
        if (d == 0) {                            // switch to folded weights
            load_wfrag_bf16((const unsigned short*)(ws + WS_WCOMB));
            bias = ((const float*)(ws + WS_BCOMB))[grow];
        }
    }
    // epilogue: x_hat_99 from h_99 (in hbuf1 after d=99)
    stage_h(1);
    if (s == 0 && wv < 4) xhat_emit(99);
}

extern "C" void kernel_launch(void* const* d_in, const int* in_sizes, int n_in,
                              void* d_out, int out_size, void* d_ws, size_t ws_size,
                              hipStream_t stream) {
    (void)in_sizes; (void)n_in; (void)out_size; (void)ws_size;
    const float* seq   = (const float*)d_in[0];
    // d_in[1] = seq_lengths (int32) -- unused by the reference forward
    const float* eps   = (const float*)d_in[2];
    const float* Wih_e = (const float*)d_in[3];
    const float* Whh_e = (const float*)d_in[4];
    const float* bih_e = (const float*)d_in[5];
    const float* bhh_e = (const float*)d_in[6];
    const float* Wmean = (const float*)d_in[7];
    const float* bmean = (const float*)d_in[8];
    const float* Wlv   = (const float*)d_in[9];
    const float* blv   = (const float*)d_in[10];
    const float* Winit = (const float*)d_in[11];
    const float* binit = (const float*)d_in[12];
    const float* Wih_d = (const float*)d_in[13];
    const float* Whh_d = (const float*)d_in[14];
    const float* bih_d = (const float*)d_in[15];
    const float* bhh_d = (const float*)d_in[16];
    const float* Wout  = (const float*)d_in[17];
    const float* bout  = (const float*)d_in[18];
    unsigned char* ws = (unsigned char*)d_ws;
    float* out = (float*)d_out;

    // zero barrier counters + hbuf0 (h0 = 0); ws is re-poisoned before each call
    hipMemsetAsync(ws, 0, WS_HBUF1, stream);
    wcomb_kernel<<<256, 256, 0, stream>>>(Wih_d, Whh_d, Wout, bih_d, bhh_d, bout, ws);
    vae_persistent<<<128, 512, 0, stream>>>(
        seq, eps, Wih_e, Whh_e, bih_e, bhh_e,
        Wmean, bmean, Wlv, blv, Winit, binit,
        Whh_d, bih_d, bhh_d, Wout, bout, ws, out);
}

// Round 4
// 2489.910 us; speedup vs baseline: 3.5370x; 3.5370x over previous
//
#include <hip/hip_runtime.h>
#include <stdint.h>

// ---------------------------------------------------------------------------
// LSTM-VAE persistent kernel, MI355X (gfx950).  B=128, T=512, I=L=64, H=512,
// 100 decoder steps.  fp32 in/out (per reference dtypes); bf16 MFMA internal.
//
// Grid: 128 WGs = 8 batch-groups(g) x 16 hidden-slices(s), block=512 (8 waves).
// Each slice owns 32 hidden dims = 128 gate rows. Gate rows interleaved
// [i0,f0,g0,o0, i1,...] so one 16x16 MFMA C-tile holds all 4 gates of 4 dims
// -> cell update needs only 3 quad shuffles.  W_hh slice (128x512) lives in
// 64 VGPRs/lane as loop-invariant MFMA B-fragments (no big LDS).
// Decoder folds x_hat via W_comb = W_hh_dec + W_ih_dec@W_out (h-only
// recurrence, one barrier/step); x_hat emitted inline by slice 0.
//
// Inter-WG sync (round-4 change): NO cache-maintenance fences (round 3's
// agent release/acquire fences = whole-L2 wb/inv per wave per step = 14 us/
// step, 96% idle). All cross-WG data (h, z, counter) moves via agent-scope
// RELAXED atomics -> sc0|sc1 global ops serviced at the device-coherent LLC.
// Ordering: producer h-stores drain at __syncthreads (vmcnt 0) before the
// counter fetch_add; consumer loads issue in-order after the spin exits.
// ---------------------------------------------------------------------------

typedef short short8 __attribute__((ext_vector_type(8)));
typedef float f32x4 __attribute__((ext_vector_type(4)));

#define WS_CNT    0
#define WS_HBUF0  4096
#define WS_HBUF1  135168
#define WS_Z      266240
#define WS_BCOMB  299008
#define WS_WCOMB  307200
// ws bytes used: 307200 + 2*1024*1024 = 2404352 (~2.3 MB)

static __device__ __forceinline__ float b2f(unsigned short u) {
    return __builtin_bit_cast(float, (unsigned int)u << 16);
}
static __device__ __forceinline__ unsigned short f2b(float f) {
    unsigned int u = __builtin_bit_cast(unsigned int, f);
    unsigned int r = u + 0x7FFFu + ((u >> 16) & 1u);  // RNE
    return (unsigned short)(r >> 16);
}
static __device__ __forceinline__ float sigm(float x)  { return 1.0f / (1.0f + __expf(-x)); }
static __device__ __forceinline__ float tanhx(float x) { return 1.0f - 2.0f / (__expf(2.0f * x) + 1.0f); }

// convert 8 consecutive fp32 (32B-aligned) to a bf16 short8 fragment
static __device__ __forceinline__ short8 cvt8(const float* p) {
    const float4 a = ((const float4*)p)[0];
    const float4 b = ((const float4*)p)[1];
    short8 r;
    r[0] = (short)f2b(a.x); r[1] = (short)f2b(a.y);
    r[2] = (short)f2b(a.z); r[3] = (short)f2b(a.w);
    r[4] = (short)f2b(b.x); r[5] = (short)f2b(b.y);
    r[6] = (short)f2b(b.z); r[7] = (short)f2b(b.w);
    return r;
}

// ---------------------------------------------------------------------------
// Kernel 1: W_comb = W_hh_dec + W_ih_dec @ W_out (bf16 out), b_comb (fp32)
// ---------------------------------------------------------------------------
__global__ void __launch_bounds__(256)
wcomb_kernel(const float* __restrict__ Wih_d,
             const float* __restrict__ Whh_d,
             const float* __restrict__ Wout,
             const float* __restrict__ bih_d,
             const float* __restrict__ bhh_d,
             const float* __restrict__ bout,
             unsigned char* __restrict__ ws)
{
    __shared__ float Ash[64][64];   // W_ih_dec tile [g][i]
    __shared__ float Bsh[64][65];   // W_out tile [i][h]
    const int bid = blockIdx.x, t = threadIdx.x;
    const int gt0 = (bid >> 3) * 64, ht0 = (bid & 7) * 64;
    for (int j = 0; j < 16; ++j) {
        int idx = t + j * 256;          // 0..4095
        int r = idx >> 6, c = idx & 63;
        Ash[r][c] = Wih_d[(size_t)(gt0 + r) * 64 + c];
        Bsh[r][c] = Wout[(size_t)r * 512 + ht0 + c];
    }
    __syncthreads();
    const int gl = t >> 2, hl0 = (t & 3) * 16;
    for (int hh = 0; hh < 16; ++hh) {
        float acc = 0.f;
        #pragma unroll
        for (int i = 0; i < 64; ++i) acc += Ash[gl][i] * Bsh[i][hl0 + hh];
        int g = gt0 + gl, h = ht0 + hl0 + hh;
        float v = Whh_d[(size_t)g * 512 + h] + acc;
        ((unsigned short*)(ws + WS_WCOMB))[(size_t)g * 512 + h] = f2b(v);
    }
    if ((bid & 7) == 0 && t < 64) {
        int g = gt0 + t;
        float acc = bih_d[g] + bhh_d[g];
        #pragma unroll
        for (int i = 0; i < 64; ++i) acc += bout[i] * Ash[t][i];
        ((float*)(ws + WS_BCOMB))[g] = acc;
    }
}

// ---------------------------------------------------------------------------
// Kernel 2: persistent encoder + VAE + decoder (emits x_hat inline)
// ---------------------------------------------------------------------------
__global__ void __launch_bounds__(512, 2)
vae_persistent(const float* __restrict__ seq,
               const float* __restrict__ eps,
               const float* __restrict__ Wih_e,
               const float* __restrict__ Whh_e,
               const float* __restrict__ bih_e,
               const float* __restrict__ bhh_e,
               const float* __restrict__ Wmean,
               const float* __restrict__ bmean,
               const float* __restrict__ Wlv,
               const float* __restrict__ blv,
               const float* __restrict__ Winit,
               const float* __restrict__ binit,
               const float* __restrict__ Whh_d,
               const float* __restrict__ bih_d,
               const float* __restrict__ bhh_d,
               const float* __restrict__ Wout,
               const float* __restrict__ bout,
               unsigned char* __restrict__ ws,
               float* __restrict__ out)
{
    __shared__ __align__(16) short Al[16 * 520];  // staged h tile (bf16), stride 520
    __shared__ __align__(16) short Ho[512];       // h write-back staging [16][32]
    __shared__ float fbuf[128];                   // mean/logvar scratch
    __shared__ float zl[16 * 64];                 // z tile (fp32)

    const int tid  = threadIdx.x;
    const int g    = blockIdx.x & 7;        // batch group (XCD-aligned if round-robin)
    const int s    = blockIdx.x >> 3;       // hidden slice
    const int b0   = g * 16;
    const int lane = tid & 63;
    const int wv   = tid >> 6;              // wave 0..7
    const int col  = lane & 15;
    const int q    = lane >> 4;
    const int nloc = wv * 16 + col;         // interleaved gate column 0..127
    const int gt   = nloc & 3;              // 0=i,1=f,2=g,3=o
    const int hds  = nloc >> 2;             // hidden dim within slice
    const int grow = gt * 512 + s * 32 + hds;   // global gate row in [0,2048)

    uint32_t* cnt = (uint32_t*)(ws + WS_CNT) + g * 32;
    unsigned long long* hbuf0 = (unsigned long long*)(ws + WS_HBUF0);
    unsigned long long* hbuf1 = (unsigned long long*)(ws + WS_HBUF1);
    uint32_t* zbuf = (uint32_t*)(ws + WS_Z);

    int epoch = 0;
    float cst[4] = {0.f, 0.f, 0.f, 0.f};    // fp32 cell state (4 batch rows)

    // fence-free barrier: relaxed agent atomics at LLC (the coherence point)
    auto barrier = [&]() {
        ++epoch;
        __syncthreads();                     // drains this WG's vmem (vmcnt 0)
        if (tid == 0) {
            __hip_atomic_fetch_add(cnt, 1u, __ATOMIC_RELAXED, __HIP_MEMORY_SCOPE_AGENT);
            while (__hip_atomic_load(cnt, __ATOMIC_RELAXED, __HIP_MEMORY_SCOPE_AGENT)
                   < (uint32_t)(16 * epoch))
                __builtin_amdgcn_s_sleep(1);
        }
        __syncthreads();
    };

    // stage h[b0..b0+16][0:512] (bf16) from hbuf[p] into Al via LLC atomics
    auto stage_h = [&](int p) {
        const unsigned long long* src = p ? hbuf1 : hbuf0;
        unsigned long long* dst = (unsigned long long*)Al;
        #pragma unroll
        for (int j = 0; j < 4; ++j) {
            int idx = tid + j * 512;             // 0..2047
            int b = idx >> 7, c2 = idx & 127;    // u64 col
            unsigned long long v = __hip_atomic_load(
                src + (size_t)(b0 + b) * 128 + c2,
                __ATOMIC_RELAXED, __HIP_MEMORY_SCOPE_AGENT);
            dst[b * 130 + c2] = v;               // 130 u64 = 520 shorts stride
        }
        __syncthreads();
    };

    // loop-invariant B-fragments of the 128x512 weight slice (64 VGPRs)
    short8 wfrag[16];
    auto load_wfrag_f32 = [&](const float* Wsrc) {
        #pragma unroll
        for (int kt = 0; kt < 16; ++kt)
            wfrag[kt] = cvt8(Wsrc + (size_t)grow * 512 + kt * 32 + q * 8);
    };
    auto load_wfrag_bf16 = [&](const unsigned short* Wsrc) {
        #pragma unroll
        for (int kt = 0; kt < 16; ++kt)
            wfrag[kt] = *(const short8*)((const short*)Wsrc +
                         (size_t)grow * 512 + kt * 32 + q * 8);
    };

    // activations + cell update + bf16 h write-back to hbuf[p_write] (atomics)
    auto cell_update = [&](f32x4 acc, int p_write) {
        float act[4];
        #pragma unroll
        for (int r = 0; r < 4; ++r)
            act[r] = (gt == 2) ? tanhx(acc[r]) : sigm(acc[r]);
        int base = lane & ~3;
        #pragma unroll
        for (int r = 0; r < 4; ++r) {
            float vi = __shfl(act[r], base + 0);
            float vf = __shfl(act[r], base + 1);
            float vg = __shfl(act[r], base + 2);
            float vo = __shfl(act[r], base + 3);
            cst[r] = vf * cst[r] + vi * vg;
            act[r] = vo * tanhx(cst[r]);         // now h
        }
        if (gt == 0) {
            int hd4 = wv * 4 + (col >> 2);       // == hds, 0..31
            #pragma unroll
            for (int r = 0; r < 4; ++r)
                Ho[(q * 4 + r) * 32 + hd4] = (short)f2b(act[r]);
        }
        __syncthreads();
        if (tid < 128) {                         // 16 b x 8 u64 = 32 dims
            int b = tid >> 3, q4 = tid & 7;
            unsigned long long v = ((const unsigned long long*)Ho)[b * 8 + q4];
            unsigned long long* dst = p_write ? hbuf1 : hbuf0;
            __hip_atomic_store(dst + (size_t)(b0 + b) * 128 + s * 8 + q4, v,
                               __ATOMIC_RELAXED, __HIP_MEMORY_SCOPE_AGENT);
        }
    };

    // ---------------- encoder: 512 steps ----------------
    load_wfrag_f32(Whh_e);
    short8 xwf[2];
    #pragma unroll
    for (int kt = 0; kt < 2; ++kt)
        xwf[kt] = cvt8(Wih_e + (size_t)grow * 64 + kt * 32 + q * 8);
    const float bias_e = bih_e[grow] + bhh_e[grow];

    short8 xf[2];
    {   // prefetch x for t=0
        const float* xs = seq + ((size_t)(b0 + col) * 512 + 0) * 64 + q * 8;
        xf[0] = cvt8(xs);
        xf[1] = cvt8(xs + 32);
    }
    for (int t = 0; t < 512; ++t) {
        stage_h(t & 1);
        f32x4 acc = {bias_e, bias_e, bias_e, bias_e};
        acc = __builtin_amdgcn_mfma_f32_16x16x32_bf16(xf[0], xwf[0], acc, 0, 0, 0);
        acc = __builtin_amdgcn_mfma_f32_16x16x32_bf16(xf[1], xwf[1], acc, 0, 0, 0);
        if (t < 511) {                           // prefetch x for t+1
            const float* xs = seq + ((size_t)(b0 + col) * 512 + t + 1) * 64 + q * 8;
            xf[0] = cvt8(xs);
            xf[1] = cvt8(xs + 32);
        }
        #pragma unroll
        for (int kt = 0; kt < 16; ++kt) {
            short8 a = *(const short8*)(Al + col * 520 + kt * 32 + q * 8);
            acc = __builtin_amdgcn_mfma_f32_16x16x32_bf16(a, wfrag[kt], acc, 0, 0, 0);
        }
        cell_update(acc, (t + 1) & 1);
        barrier();
    }
    // h_n now in hbuf0

    // ---------------- VAE reparameterization ----------------
    stage_h(0);
    if (tid < 128) {
        int which = tid >> 6, idx = tid & 63;
        int b = idx >> 2, ldl = idx & 3;
        int ld = s * 4 + ldl;
        const float* wrow = (which ? Wlv : Wmean) + (size_t)ld * 512;
        float a = (which ? blv[ld] : bmean[ld]);
        for (int k = 0; k < 512; ++k)
            a += b2f((unsigned short)Al[b * 520 + k]) * wrow[k];
        out[819200 + which * 8192 + (size_t)(b0 + b) * 64 + ld] = a;
        fbuf[which * 64 + idx] = a;
    }
    __syncthreads();
    if (tid < 64) {
        int b = tid >> 2, ldl = tid & 3;
        int ld = s * 4 + ldl;
        float m = fbuf[tid], lv = fbuf[64 + tid];
        float e = eps[(size_t)(b0 + b) * 64 + ld];
        float z = m + e * __expf(0.5f * lv);
        __hip_atomic_store(zbuf + (size_t)(b0 + b) * 64 + ld,
                           __builtin_bit_cast(uint32_t, z),
                           __ATOMIC_RELAXED, __HIP_MEMORY_SCOPE_AGENT);
    }
    barrier();                                   // z visible group-wide

    // h_dec0 = z @ W_init^T + b_init
    #pragma unroll
    for (int j = 0; j < 2; ++j) {
        int idx = tid + j * 512;
        int b = idx >> 6, l = idx & 63;
        uint32_t v = __hip_atomic_load(zbuf + (size_t)(b0 + b) * 64 + l,
                                       __ATOMIC_RELAXED, __HIP_MEMORY_SCOPE_AGENT);
        zl[b * 64 + l] = __builtin_bit_cast(float, v);
    }
    __syncthreads();
    {
        int b = tid >> 5, hdl = tid & 31;
        int hd = s * 32 + hdl;
        float a = binit[hd];
        const float* wr = Winit + (size_t)hd * 64;
        #pragma unroll
        for (int l = 0; l < 64; ++l) a += zl[b * 64 + l] * wr[l];
        Ho[b * 32 + hdl] = (short)f2b(a);
    }
    __syncthreads();
    if (tid < 128) {
        int b = tid >> 3, q4 = tid & 7;
        unsigned long long v = ((const unsigned long long*)Ho)[b * 8 + q4];
        __hip_atomic_store(hbuf1 + (size_t)(b0 + b) * 128 + s * 8 + q4, v,
                           __ATOMIC_RELAXED, __HIP_MEMORY_SCOPE_AGENT);
    }
    #pragma unroll
    for (int r = 0; r < 4; ++r) cst[r] = 0.f;
    barrier();                                   // h_dec0 visible (in hbuf1)

    // ---------------- decoder: 100 steps + inline x_hat ----------------
    short8 wof[16];
    float xbias = 0.f;
    if (wv < 4) {                                // x_hat fragments (waves 0-3)
        xbias = bout[wv * 16 + col];
        #pragma unroll
        for (int kt = 0; kt < 16; ++kt)
            wof[kt] = cvt8(Wout + (size_t)(wv * 16 + col) * 512 + kt * 32 + q * 8);
    }
    auto xhat_emit = [&](int d) {                // x_hat_d from Al (s==0, wv<4)
        f32x4 a2 = {xbias, xbias, xbias, xbias};
        #pragma unroll
        for (int kt = 0; kt < 16; ++kt) {
            short8 a = *(const short8*)(Al + col * 520 + kt * 32 + q * 8);
            a2 = __builtin_amdgcn_mfma_f32_16x16x32_bf16(a, wof[kt], a2, 0, 0, 0);
        }
        #pragma unroll
        for (int r = 0; r < 4; ++r) {
            int b = q * 4 + r;
            out[((size_t)(b0 + b) * 100 + d) * 64 + wv * 16 + col] = a2[r];
        }
    };

    load_wfrag_f32(Whh_d);                       // step 0: x0 == 0
    float bias = bih_d[grow] + bhh_d[grow];
    for (int d = 0; d < 100; ++d) {
        stage_h((d + 1) & 1);                    // Al = h_{d-1} (or h_dec0)
        if (d >= 1 && s == 0 && wv < 4) xhat_emit(d - 1);
        f32x4 acc = {bias, bias, bias, bias};
        #pragma unroll
        for (int kt = 0; kt < 16; ++kt) {
            short8 a = *(const short8*)(Al + col * 520 + kt * 32 + q * 8);
            acc = __builtin_amdgcn_mfma_f32_16x16x32_bf16(a, wfrag[kt], acc, 0, 0, 0);
        }
        cell_update(acc, d & 1);
        barrier();
        if (d == 0) {                            // switch to folded weights
            load_wfrag_bf16((const unsigned short*)(ws + WS_WCOMB));
            bias = ((const float*)(ws + WS_BCOMB))[grow];
        }
    }
    // epilogue: x_hat_99 from h_99 (in hbuf1 after d=99)
    stage_h(1);
    if (s == 0 && wv < 4) xhat_emit(99);
}

extern "C" void kernel_launch(void* const* d_in, const int* in_sizes, int n_in,
                              void* d_out, int out_size, void* d_ws, size_t ws_size,
                              hipStream_t stream) {
    (void)in_sizes; (void)n_in; (void)out_size; (void)ws_size;
    const float* seq   = (const float*)d_in[0];
    // d_in[1] = seq_lengths (int32) -- unused by the reference forward
    const float* eps   = (const float*)d_in[2];
    const float* Wih_e = (const float*)d_in[3];
    const float* Whh_e = (const float*)d_in[4];
    const float* bih_e = (const float*)d_in[5];
    const float* bhh_e = (const float*)d_in[6];
    const float* Wmean = (const float*)d_in[7];
    const float* bmean = (const float*)d_in[8];
    const float* Wlv   = (const float*)d_in[9];
    const float* blv   = (const float*)d_in[10];
    const float* Winit = (const float*)d_in[11];
    const float* binit = (const float*)d_in[12];
    const float* Wih_d = (const float*)d_in[13];
    const float* Whh_d = (const float*)d_in[14];
    const float* bih_d = (const float*)d_in[15];
    const float* bhh_d = (const float*)d_in[16];
    const float* Wout  = (const float*)d_in[17];
    const float* bout  = (const float*)d_in[18];
    unsigned char* ws = (unsigned char*)d_ws;
    float* out = (float*)d_out;

    // zero barrier counters + hbuf0 (h0 = 0); ws is re-poisoned before each call
    hipMemsetAsync(ws, 0, WS_HBUF1, stream);
    wcomb_kernel<<<256, 256, 0, stream>>>(Wih_d, Whh_d, Wout, bih_d, bhh_d, bout, ws);
    vae_persistent<<<128, 512, 0, stream>>>(
        seq, eps, Wih_e, Whh_e, bih_e, bhh_e,
        Wmean, bmean, Wlv, blv, Winit, binit,
        Whh_d, bih_d, bhh_d, Wout, bout, ws, out);
}

// Round 5
// 2392.744 us; speedup vs baseline: 3.6806x; 1.0406x over previous
//
#include <hip/hip_runtime.h>
#include <stdint.h>

// ---------------------------------------------------------------------------
// LSTM-VAE persistent kernel, MI355X (gfx950).  B=128, T=512, I=L=64, H=512,
// 100 decoder steps.  fp32 in/out; bf16 MFMA internal.
//
// 128 WGs = 8 batch-groups(g) x 16 hidden-slices(s), block=512 (8 waves).
// Slice owns 32 hidden dims = 128 interleaved gate rows [i0,f0,g0,o0,i1,...];
// W_hh slice in 64 VGPRs/lane as loop-invariant MFMA B-fragments.
// Decoder folds x_hat via W_comb = W_hh_dec + W_ih_dec@W_out.
//
// Round-5 sync: per-slice FLAG WORDS on separate 128-B lines (no RMW
// counter). Producer = wave 0 only: 2 u64 agent-relaxed atomic h-stores,
// s_waitcnt vmcnt(0), then flag[s]=round. Consumers: wave 0 polls the 16
// flags (pure reads), one __syncthreads releases the WG, then all waves
// stage h via agent-relaxed u64 atomic loads (LLC is the coherence point;
// no cache-maintenance fences anywhere - round 3 showed those cost 14us/step).
// Round r's h lives in hbuf[r&1]; flag[s]>=r certifies slice s stored round r
// (and therefore finished reading round r-1, making buffer reuse safe).
// ---------------------------------------------------------------------------

typedef short short8 __attribute__((ext_vector_type(8)));
typedef float f32x4 __attribute__((ext_vector_type(4)));

#define WS_FLAGS  0                       // 8 groups x 16 slices x 128 B
#define WS_HBUF0  16384                   // 128 KB
#define WS_HBUF1  147456                  // 128 KB
#define WS_Z      278528                  // 32 KB fp32
#define WS_BCOMB  311296                  // 8 KB fp32
#define WS_WCOMB  319488                  // 2 MB bf16
#define WS_SEQB   2416640                 // 8 MB bf16 seq
#define WS_END    10805248
#define WS_ZERO   WS_HBUF1                // flags + hbuf0 must be zeroed

static __device__ __forceinline__ float b2f(unsigned short u) {
    return __builtin_bit_cast(float, (unsigned int)u << 16);
}
static __device__ __forceinline__ unsigned short f2b(float f) {
    unsigned int u = __builtin_bit_cast(unsigned int, f);
    unsigned int r = u + 0x7FFFu + ((u >> 16) & 1u);  // RNE
    return (unsigned short)(r >> 16);
}
static __device__ __forceinline__ float sigm(float x)  { return 1.0f / (1.0f + __expf(-x)); }
static __device__ __forceinline__ float tanhx(float x) { return 1.0f - 2.0f / (__expf(2.0f * x) + 1.0f); }

static __device__ __forceinline__ short8 cvt8(const float* p) {
    const float4 a = ((const float4*)p)[0];
    const float4 b = ((const float4*)p)[1];
    short8 r;
    r[0] = (short)f2b(a.x); r[1] = (short)f2b(a.y);
    r[2] = (short)f2b(a.z); r[3] = (short)f2b(a.w);
    r[4] = (short)f2b(b.x); r[5] = (short)f2b(b.y);
    r[6] = (short)f2b(b.z); r[7] = (short)f2b(b.w);
    return r;
}

// ---------------------------------------------------------------------------
// Prologue A: seq fp32 -> bf16 (one-time, parallel)
// ---------------------------------------------------------------------------
__global__ void __launch_bounds__(256)
seqcvt_kernel(const float* __restrict__ src, unsigned short* __restrict__ dst)
{
    int i = (blockIdx.x * 256 + threadIdx.x) * 4;   // 4 floats each
    float4 v = *(const float4*)(src + i);
    uint32_t lo = (uint32_t)f2b(v.x) | ((uint32_t)f2b(v.y) << 16);
    uint32_t hi = (uint32_t)f2b(v.z) | ((uint32_t)f2b(v.w) << 16);
    uint2 o; o.x = lo; o.y = hi;
    *(uint2*)(dst + i) = o;
}

// ---------------------------------------------------------------------------
// Prologue B: W_comb = W_hh_dec + W_ih_dec @ W_out (bf16 out), b_comb (fp32)
// ---------------------------------------------------------------------------
__global__ void __launch_bounds__(256)
wcomb_kernel(const float* __restrict__ Wih_d,
             const float* __restrict__ Whh_d,
             const float* __restrict__ Wout,
             const float* __restrict__ bih_d,
             const float* __restrict__ bhh_d,
             const float* __restrict__ bout,
             unsigned char* __restrict__ ws)
{
    __shared__ float Ash[64][64];   // W_ih_dec tile [g][i]
    __shared__ float Bsh[64][65];   // W_out tile [i][h]
    const int bid = blockIdx.x, t = threadIdx.x;
    const int gt0 = (bid >> 3) * 64, ht0 = (bid & 7) * 64;
    for (int j = 0; j < 16; ++j) {
        int idx = t + j * 256;
        int r = idx >> 6, c = idx & 63;
        Ash[r][c] = Wih_d[(size_t)(gt0 + r) * 64 + c];
        Bsh[r][c] = Wout[(size_t)r * 512 + ht0 + c];
    }
    __syncthreads();
    const int gl = t >> 2, hl0 = (t & 3) * 16;
    for (int hh = 0; hh < 16; ++hh) {
        float acc = 0.f;
        #pragma unroll
        for (int i = 0; i < 64; ++i) acc += Ash[gl][i] * Bsh[i][hl0 + hh];
        int g = gt0 + gl, h = ht0 + hl0 + hh;
        float v = Whh_d[(size_t)g * 512 + h] + acc;
        ((unsigned short*)(ws + WS_WCOMB))[(size_t)g * 512 + h] = f2b(v);
    }
    if ((bid & 7) == 0 && t < 64) {
        int g = gt0 + t;
        float acc = bih_d[g] + bhh_d[g];
        #pragma unroll
        for (int i = 0; i < 64; ++i) acc += bout[i] * Ash[t][i];
        ((float*)(ws + WS_BCOMB))[g] = acc;
    }
}

// ---------------------------------------------------------------------------
// Main persistent kernel
// ---------------------------------------------------------------------------
__global__ void __launch_bounds__(512, 2)
vae_persistent(const float* __restrict__ seq,
               const unsigned short* __restrict__ seqb,   // bf16 seq or null
               const float* __restrict__ eps,
               const float* __restrict__ Wih_e,
               const float* __restrict__ Whh_e,
               const float* __restrict__ bih_e,
               const float* __restrict__ bhh_e,
               const float* __restrict__ Wmean,
               const float* __restrict__ bmean,
               const float* __restrict__ Wlv,
               const float* __restrict__ blv,
               const float* __restrict__ Winit,
               const float* __restrict__ binit,
               const float* __restrict__ Whh_d,
               const float* __restrict__ bih_d,
               const float* __restrict__ bhh_d,
               const float* __restrict__ Wout,
               const float* __restrict__ bout,
               unsigned char* __restrict__ ws,
               float* __restrict__ out)
{
    __shared__ __align__(16) short Al[16 * 520];  // staged h tile (bf16)
    __shared__ __align__(16) short Ho[512];       // h write-back staging [16][32]
    __shared__ float fbuf[128];                   // mean/logvar scratch
    __shared__ float zl[16 * 64];                 // z tile (fp32)

    const int tid  = threadIdx.x;
    const int g    = blockIdx.x & 7;        // batch group (same-XCD under %8 rr)
    const int s    = blockIdx.x >> 3;       // hidden slice
    const int b0   = g * 16;
    const int lane = tid & 63;
    const int wv   = tid >> 6;
    const int col  = lane & 15;
    const int q    = lane >> 4;
    const int nloc = wv * 16 + col;         // interleaved gate column 0..127
    const int gt   = nloc & 3;              // 0=i,1=f,2=g,3=o
    const int hds  = nloc >> 2;
    const int grow = gt * 512 + s * 32 + hds;

    uint32_t* flags = (uint32_t*)(ws + WS_FLAGS) + (size_t)g * 512;  // slice i @ [i*32]
    unsigned long long* hbuf0 = (unsigned long long*)(ws + WS_HBUF0);
    unsigned long long* hbuf1 = (unsigned long long*)(ws + WS_HBUF1);
    uint32_t* zbuf = (uint32_t*)(ws + WS_Z);

    float cst[4] = {0.f, 0.f, 0.f, 0.f};

    // wave 0 polls the 16 per-slice flag lines; one barrier releases the WG
    auto wait_round = [&](uint32_t r) {
        if (wv == 0 && lane < 16) {
            while (__hip_atomic_load(&flags[lane * 32], __ATOMIC_RELAXED,
                                     __HIP_MEMORY_SCOPE_AGENT) < r) {}
        }
        __syncthreads();
    };

    // stage h (round r in hbuf[r&1]) into Al
    auto stage_h = [&](uint32_t r) {
        const unsigned long long* src = (r & 1) ? hbuf1 : hbuf0;
        unsigned long long* dst = (unsigned long long*)Al;
        #pragma unroll
        for (int j = 0; j < 4; ++j) {
            int idx = tid + j * 512;
            int b = idx >> 7, c2 = idx & 127;
            unsigned long long v = __hip_atomic_load(
                src + (size_t)(b0 + b) * 128 + c2,
                __ATOMIC_RELAXED, __HIP_MEMORY_SCOPE_AGENT);
            dst[b * 130 + c2] = v;
        }
        __syncthreads();
    };

    // wave 0: gather Ho -> 2 u64 atomic stores -> drain -> flag = r_out
    auto publish_h = [&](uint32_t r_out) {
        if (wv == 0) {
            unsigned long long* dst = (r_out & 1) ? hbuf1 : hbuf0;
            int b_lo = lane >> 3, q4 = lane & 7;
            unsigned long long v0 = ((const unsigned long long*)Ho)[b_lo * 8 + q4];
            unsigned long long v1 = ((const unsigned long long*)Ho)[(b_lo + 8) * 8 + q4];
            __hip_atomic_store(dst + (size_t)(b0 + b_lo) * 128 + s * 8 + q4, v0,
                               __ATOMIC_RELAXED, __HIP_MEMORY_SCOPE_AGENT);
            __hip_atomic_store(dst + (size_t)(b0 + b_lo + 8) * 128 + s * 8 + q4, v1,
                               __ATOMIC_RELAXED, __HIP_MEMORY_SCOPE_AGENT);
            asm volatile("s_waitcnt vmcnt(0)" ::: "memory");
            if (lane == 0)
                __hip_atomic_store(&flags[s * 32], r_out, __ATOMIC_RELAXED,
                                   __HIP_MEMORY_SCOPE_AGENT);
        }
    };

    short8 wfrag[16];
    auto load_wfrag_f32 = [&](const float* Wsrc) {
        #pragma unroll
        for (int kt = 0; kt < 16; ++kt)
            wfrag[kt] = cvt8(Wsrc + (size_t)grow * 512 + kt * 32 + q * 8);
    };
    auto load_wfrag_bf16 = [&](const unsigned short* Wsrc) {
        #pragma unroll
        for (int kt = 0; kt < 16; ++kt)
            wfrag[kt] = *(const short8*)((const short*)Wsrc +
                         (size_t)grow * 512 + kt * 32 + q * 8);
    };

    // activations + cell update; leaves h slice in Ho (needs syncthreads after)
    auto cell_update = [&](f32x4 acc) {
        float act[4];
        #pragma unroll
        for (int r = 0; r < 4; ++r)
            act[r] = (gt == 2) ? tanhx(acc[r]) : sigm(acc[r]);
        int base = lane & ~3;
        #pragma unroll
        for (int r = 0; r < 4; ++r) {
            float vi = __shfl(act[r], base + 0);
            float vf = __shfl(act[r], base + 1);
            float vg = __shfl(act[r], base + 2);
            float vo = __shfl(act[r], base + 3);
            cst[r] = vf * cst[r] + vi * vg;
            act[r] = vo * tanhx(cst[r]);
        }
        if (gt == 0) {
            int hd4 = wv * 4 + (col >> 2);
            #pragma unroll
            for (int r = 0; r < 4; ++r)
                Ho[(q * 4 + r) * 32 + hd4] = (short)f2b(act[r]);
        }
    };

    // ---------------- encoder: 512 steps ----------------
    load_wfrag_f32(Whh_e);
    short8 xwf[2];
    #pragma unroll
    for (int kt = 0; kt < 2; ++kt)
        xwf[kt] = cvt8(Wih_e + (size_t)grow * 64 + kt * 32 + q * 8);
    const float bias_e = bih_e[grow] + bhh_e[grow];

    auto load_x = [&](int t, short8* xf) {
        if (seqb) {
            const short* xs = (const short*)seqb + ((size_t)(b0 + col) * 512 + t) * 64 + q * 8;
            xf[0] = *(const short8*)(xs);
            xf[1] = *(const short8*)(xs + 32);
        } else {
            const float* xs = seq + ((size_t)(b0 + col) * 512 + t) * 64 + q * 8;
            xf[0] = cvt8(xs);
            xf[1] = cvt8(xs + 32);
        }
    };

    short8 xf[2];
    load_x(0, xf);
    for (uint32_t t = 0; t < 512; ++t) {
        wait_round(t);
        stage_h(t);
        f32x4 acc = {bias_e, bias_e, bias_e, bias_e};
        acc = __builtin_amdgcn_mfma_f32_16x16x32_bf16(xf[0], xwf[0], acc, 0, 0, 0);
        acc = __builtin_amdgcn_mfma_f32_16x16x32_bf16(xf[1], xwf[1], acc, 0, 0, 0);
        if (t < 511) load_x(t + 1, xf);
        #pragma unroll
        for (int kt = 0; kt < 16; ++kt) {
            short8 a = *(const short8*)(Al + col * 520 + kt * 32 + q * 8);
            acc = __builtin_amdgcn_mfma_f32_16x16x32_bf16(a, wfrag[kt], acc, 0, 0, 0);
        }
        cell_update(acc);
        __syncthreads();
        publish_h(t + 1);
    }

    // ---------------- VAE reparameterization (round 513 = z) ----------------
    wait_round(512);
    stage_h(512);                                // Al = h_n (buffer 0)
    if (tid < 128) {
        int which = tid >> 6, idx = tid & 63;
        int b = idx >> 2, ldl = idx & 3;
        int ld = s * 4 + ldl;
        const float* wrow = (which ? Wlv : Wmean) + (size_t)ld * 512;
        float a = (which ? blv[ld] : bmean[ld]);
        for (int k = 0; k < 512; ++k)
            a += b2f((unsigned short)Al[b * 520 + k]) * wrow[k];
        out[819200 + which * 8192 + (size_t)(b0 + b) * 64 + ld] = a;
        fbuf[which * 64 + idx] = a;
    }
    __syncthreads();
    if (wv == 0) {
        int b = lane >> 2, ldl = lane & 3;
        int ld = s * 4 + ldl;
        float m = fbuf[lane], lv = fbuf[64 + lane];
        float e = eps[(size_t)(b0 + b) * 64 + ld];
        float z = m + e * __expf(0.5f * lv);
        __hip_atomic_store(zbuf + (size_t)(b0 + b) * 64 + ld,
                           __builtin_bit_cast(uint32_t, z),
                           __ATOMIC_RELAXED, __HIP_MEMORY_SCOPE_AGENT);
        asm volatile("s_waitcnt vmcnt(0)" ::: "memory");
        if (lane == 0)
            __hip_atomic_store(&flags[s * 32], 513u, __ATOMIC_RELAXED,
                               __HIP_MEMORY_SCOPE_AGENT);
    }
    wait_round(513);

    // h_dec0 = z @ W_init^T + b_init, computed LOCALLY into Al (no exchange)
    #pragma unroll
    for (int j = 0; j < 2; ++j) {
        int idx = tid + j * 512;
        int b = idx >> 6, l = idx & 63;
        uint32_t v = __hip_atomic_load(zbuf + (size_t)(b0 + b) * 64 + l,
                                       __ATOMIC_RELAXED, __HIP_MEMORY_SCOPE_AGENT);
        zl[b * 64 + l] = __builtin_bit_cast(float, v);
    }
    __syncthreads();
    {
        int b = tid >> 5, c = tid & 31;
        #pragma unroll
        for (int j = 0; j < 16; ++j) {
            int hd = c * 16 + j;
            float a = binit[hd];
            const float* wr = Winit + (size_t)hd * 64;
            #pragma unroll
            for (int l = 0; l < 64; ++l) a += zl[b * 64 + l] * wr[l];
            Al[b * 520 + hd] = (short)f2b(a);
        }
    }
    #pragma unroll
    for (int r = 0; r < 4; ++r) cst[r] = 0.f;
    __syncthreads();

    // ---------------- decoder: 100 steps, h_{d+1} = round 514+d ----------------
    short8 wof[16];
    float xbias = 0.f;
    if (wv < 4) {
        xbias = bout[wv * 16 + col];
        #pragma unroll
        for (int kt = 0; kt < 16; ++kt)
            wof[kt] = cvt8(Wout + (size_t)(wv * 16 + col) * 512 + kt * 32 + q * 8);
    }
    auto xhat_emit = [&](int d) {                // x_hat_d = Al @ Wout^T (Al=h_{d+1})
        f32x4 a2 = {xbias, xbias, xbias, xbias};
        #pragma unroll
        for (int kt = 0; kt < 16; ++kt) {
            short8 a = *(const short8*)(Al + col * 520 + kt * 32 + q * 8);
            a2 = __builtin_amdgcn_mfma_f32_16x16x32_bf16(a, wof[kt], a2, 0, 0, 0);
        }
        #pragma unroll
        for (int r = 0; r < 4; ++r) {
            int b = q * 4 + r;
            out[((size_t)(b0 + b) * 100 + d) * 64 + wv * 16 + col] = a2[r];
        }
    };

    load_wfrag_f32(Whh_d);                       // step 0: x0 == 0
    float bias = bih_d[grow] + bhh_d[grow];
    for (uint32_t d = 0; d < 100; ++d) {
        if (d > 0) {
            wait_round(513 + d);
            stage_h(513 + d);                    // Al = h_d
        }
        f32x4 acc = {bias, bias, bias, bias};
        #pragma unroll
        for (int kt = 0; kt < 16; ++kt) {
            short8 a = *(const short8*)(Al + col * 520 + kt * 32 + q * 8);
            acc = __builtin_amdgcn_mfma_f32_16x16x32_bf16(a, wfrag[kt], acc, 0, 0, 0);
        }
        cell_update(acc);
        __syncthreads();
        publish_h(514 + d);
        if (d >= 1 && s == 0 && wv < 4) xhat_emit(d - 1);  // hidden under wait
        if (d == 0) {
            load_wfrag_bf16((const unsigned short*)(ws + WS_WCOMB));
            bias = ((const float*)(ws + WS_BCOMB))[grow];
        }
    }
    // epilogue: x_hat_99 from h_100 (round 613, buffer 1)
    wait_round(613);
    stage_h(613);
    if (s == 0 && wv < 4) xhat_emit(99);
}

extern "C" void kernel_launch(void* const* d_in, const int* in_sizes, int n_in,
                              void* d_out, int out_size, void* d_ws, size_t ws_size,
                              hipStream_t stream) {
    (void)in_sizes; (void)n_in; (void)out_size;
    const float* seq   = (const float*)d_in[0];
    const float* eps   = (const float*)d_in[2];
    const float* Wih_e = (const float*)d_in[3];
    const float* Whh_e = (const float*)d_in[4];
    const float* bih_e = (const float*)d_in[5];
    const float* bhh_e = (const float*)d_in[6];
    const float* Wmean = (const float*)d_in[7];
    const float* bmean = (const float*)d_in[8];
    const float* Wlv   = (const float*)d_in[9];
    const float* blv   = (const float*)d_in[10];
    const float* Winit = (const float*)d_in[11];
    const float* binit = (const float*)d_in[12];
    const float* Wih_d = (const float*)d_in[13];
    const float* Whh_d = (const float*)d_in[14];
    const float* bih_d = (const float*)d_in[15];
    const float* bhh_d = (const float*)d_in[16];
    const float* Wout  = (const float*)d_in[17];
    const float* bout  = (const float*)d_in[18];
    unsigned char* ws = (unsigned char*)d_ws;
    float* out = (float*)d_out;

    const bool have_seqb = ws_size >= (size_t)WS_END;
    unsigned short* seqb = have_seqb ? (unsigned short*)(ws + WS_SEQB) : nullptr;

    hipMemsetAsync(ws, 0, WS_ZERO, stream);      // flags + hbuf0 (h0 = 0)
    if (have_seqb)
        seqcvt_kernel<<<4096, 256, 0, stream>>>(seq, seqb);
    wcomb_kernel<<<256, 256, 0, stream>>>(Wih_d, Whh_d, Wout, bih_d, bhh_d, bout, ws);
    vae_persistent<<<128, 512, 0, stream>>>(
        seq, seqb, eps, Wih_e, Whh_e, bih_e, bhh_e,
        Wmean, bmean, Wlv, blv, Winit, binit,
        Whh_d, bih_d, bhh_d, Wout, bout, ws, out);
}